// Round 13
// baseline (293.971 us; speedup 1.0000x reference)
//
#include <hip/hip_runtime.h>
#include <math.h>

#define DIM 1024
#define SCALE 0.125f
#define NT 16  // K-tiles of 64

typedef __attribute__((ext_vector_type(8))) short bh8;
typedef __attribute__((ext_vector_type(4))) short bh4;
typedef __attribute__((ext_vector_type(4))) float f4v;
typedef __attribute__((ext_vector_type(16))) float f16v;

__device__ __forceinline__ unsigned short f2bf(float f) {
  unsigned u = __builtin_bit_cast(unsigned, f);
  return (unsigned short)((u + 0x7FFFu + ((u >> 16) & 1u)) >> 16);
}
__device__ __forceinline__ float bf2f(unsigned short u) {
  return __builtin_bit_cast(float, (unsigned)u << 16);
}
__device__ __forceinline__ float elu1(float v) {
  return v > 0.f ? v + 1.f : __expf(v);
}
__device__ __forceinline__ f4v mfma16(bh8 a, bh8 b, f4v c) {
  return __builtin_amdgcn_mfma_f32_16x16x32_bf16(a, b, c, 0, 0, 0);
}
__device__ __forceinline__ f16v mfma32(bh8 a, bh8 b, f16v c) {
  return __builtin_amdgcn_mfma_f32_32x32x16_bf16(a, b, c, 0, 0, 0);
}

typedef const void __attribute__((address_space(1)))* gas1_t;
typedef void __attribute__((address_space(3)))* las3_t;

// 128x64 bf16 half-tile in LDS as 1024 16B chunks, swizzle q = c ^ ((c>>3)&7)
__device__ __forceinline__ bh8 frag(const unsigned short* lds, int row, int k8) {
  const int q = ((row << 3) | k8) ^ (row & 7);
  return *reinterpret_cast<const bh8*>(lds + q * 8);
}

// 256-thread staging helper (used by g3): 128x64 tile, 4 chunks/thread
__device__ __forceinline__ void gll_tile(const unsigned short* g, int ldg,
                                         unsigned short* lds, int t) {
  const int lane = t & 63, w = t >> 6;
#pragma unroll
  for (int cc = 0; cc < 4; ++cc) {
    const int base = (w * 4 + cc) * 64;
    const int q = base + lane;
    const int c = q ^ ((q >> 3) & 7);
    __builtin_amdgcn_global_load_lds(
        (gas1_t)(const void*)(g + (size_t)(c >> 3) * ldg + (c & 7) * 8),
        (las3_t)(void*)(lds + (size_t)base * 8), 16, 0, 0);
  }
}

// ---- P01: fused x-cvt (blocks < np0) + weight transpose (first pass only) --
__global__ __launch_bounds__(256) void p01(
    const float* __restrict__ x, unsigned short* __restrict__ xb, int np0,
    const float* __restrict__ Wq, const float* __restrict__ Wk,
    const float* __restrict__ Wv, const float* __restrict__ Wg,
    const float* __restrict__ Wo, unsigned short* __restrict__ WallT,
    unsigned short* __restrict__ WoT, int do_w) {
  const int bid = (int)blockIdx.x;
  const int t = (int)threadIdx.x;
  if (bid < np0) {
    const size_t i = ((size_t)bid * 256 + t) * 8;
    const float4 a = *reinterpret_cast<const float4*>(x + i);
    const float4 b = *reinterpret_cast<const float4*>(x + i + 4);
    bh8 v;
    v[0] = (short)f2bf(a.x); v[1] = (short)f2bf(a.y);
    v[2] = (short)f2bf(a.z); v[3] = (short)f2bf(a.w);
    v[4] = (short)f2bf(b.x); v[5] = (short)f2bf(b.y);
    v[6] = (short)f2bf(b.z); v[7] = (short)f2bf(b.w);
    *reinterpret_cast<bh8*>(xb + i) = v;
    return;
  }
  if (!do_w) return;
  const int rem = bid - np0;
  const int m = rem >> 8;          // 0..4
  const int tc = rem & 15, tr = (rem >> 4) & 15;
  const float* src = m == 0 ? Wq : m == 1 ? Wk : m == 2 ? Wv : m == 3 ? Wg : Wo;
  __shared__ float tile[64][65];
#pragma unroll
  for (int i = 0; i < 4; ++i) {
    const int idx = i * 256 + t;
    const int r = idx >> 4;
    const int c4 = (idx & 15) * 4;
    const float4 v = *reinterpret_cast<const float4*>(
        src + (size_t)(tr * 64 + r) * DIM + tc * 64 + c4);
    tile[r][c4] = v.x; tile[r][c4 + 1] = v.y;
    tile[r][c4 + 2] = v.z; tile[r][c4 + 3] = v.w;
  }
  __syncthreads();
  unsigned short* dst = (m < 4) ? WallT : WoT;
#pragma unroll
  for (int i = 0; i < 4; ++i) {
    const int idx = i * 256 + t;
    const int lc = idx >> 4;
    const int k4i = (idx & 15) * 4;
    const size_t drow = (m < 4) ? (size_t)(tc * 256 + m * 64 + lc)
                                : (size_t)(tc * 64 + lc);
    bh4 v;
#pragma unroll
    for (int jj = 0; jj < 4; ++jj) v[jj] = (short)f2bf(tile[k4i + jj][lc]);
    *reinterpret_cast<bh4*>(dst + drow * DIM + tr * 64 + k4i) = v;
  }
}

// ---- gemm8: 256x256 tile, round-5 phase pipeline, 32x32x16 MFMA -------------
// MODE 0: qkvg = xb @ WallT^T, fused activations + kv/ksum partials;
//         only q,g columns stored to global (k,v are epilogue-consumed only)
// MODE 1: out = attn(dense, in xb) @ WoT^T, f32 out (1024 cols)
template <int MODE>
__global__ __launch_bounds__(512, 1) void gemm8(
    const unsigned short* __restrict__ gA,
    const unsigned short* __restrict__ gB, const float* __restrict__ bg,
    unsigned short* __restrict__ ob, float* __restrict__ of,
    float* __restrict__ kv_part, float* __restrict__ ksum_part) {
  const int t = threadIdx.x, lane = t & 63, w = t >> 6;
  const int wr = w >> 2, wc = w & 3, g4 = lane >> 4, c0 = lane & 15;
  const int c31 = lane & 31, hi5 = lane >> 5;
  const int nwg = gridDim.x;
  const int NBC = (MODE == 0) ? 16 : 4;
  const int rbn = nwg / NBC;
  // XCD row-band swizzle: XCD x owns rb in [x*bandsz, (x+1)*bandsz), cb-major
  const int bid = (int)blockIdx.x;
  const int xcd = bid & 7;
  const int idx = bid >> 3;
  const int bandsz = rbn >> 3;
  const int cb = idx / bandsz;
  const int rb = xcd * bandsz + (idx - cb * bandsz);

  __shared__ __align__(16) unsigned short lds[65536];  // 128 KiB

  // per-thread chunk offsets (2 chunks per half-tile stage)
  int offA[2], offB[2], dstc[2];
#pragma unroll
  for (int cc = 0; cc < 2; ++cc) {
    const int base = (w * 2 + cc) * 64;
    const int q = base + lane;
    const int c = q ^ ((q >> 3) & 7);
    offA[cc] = (c >> 3) * 1024 + (c & 7) * 8;
    offB[cc] = (c >> 3) * 1024 + (c & 7) * 8;
    dstc[cc] = base * 8;
  }
  const unsigned short* Abase = gA + (size_t)rb * 256 * 1024;
  const unsigned short* Bbase = gB + (size_t)cb * 256 * 1024;

#define SA(kt, half)                                                          \
  {                                                                           \
    _Pragma("unroll") for (int cc = 0; cc < 2; ++cc)                          \
        __builtin_amdgcn_global_load_lds(                                     \
            (gas1_t)(Abase + (size_t)(half) * 128 * 1024 + offA[cc] +         \
                     (kt) * 64),                                              \
            (las3_t)(lds + ((kt) & 1) * 16384 + (half) * 8192 + dstc[cc]),    \
            16, 0, 0);                                                        \
  }
#define SB(kt, half)                                                          \
  {                                                                           \
    _Pragma("unroll") for (int cc = 0; cc < 2; ++cc)                          \
        __builtin_amdgcn_global_load_lds(                                     \
            (gas1_t)(Bbase + (size_t)(half) * 128 * 1024 + offB[cc] +         \
                     (kt) * 64),                                              \
            (las3_t)(lds + 32768 + ((kt) & 1) * 16384 + (half) * 8192 +       \
                     dstc[cc]),                                               \
            16, 0, 0);                                                        \
  }

  // acc[rf][nf]: rf = 32-row fragment (4), nf = 32-col fragment (2)
  f16v acc[4][2];
#pragma unroll
  for (int i = 0; i < 4; ++i)
#pragma unroll
    for (int j = 0; j < 2; ++j)
#pragma unroll
      for (int e = 0; e < 16; ++e) acc[i][j][e] = 0.f;

  // prologue: B(0), A(0) (awaited at tile 0), then B(1) halves (in flight)
  SB(0, 0); SB(0, 1); SA(0, 0); SA(0, 1); SB(1, 0); SB(1, 1);

// A-frag for 32x32x16: lane reads row rf*32+(lane&31), k8 = kf*2 + (lane>>5)
#define AFRAG(RF, KF) frag(Ah, (RF) * 32 + c31, (KF) * 2 + hi5)
#define BFRAG(NF, KF) frag(Bh, br0 + (NF) * 32 + c31, (KF) * 2 + hi5)

#pragma unroll 2
  for (int kt = 0; kt < NT; ++kt) {
    // top-of-tile: all of tile kt landed; B(kt+1) halves may pend (4 loads)
    if (kt < NT - 1) {
      asm volatile("s_waitcnt vmcnt(4)" ::: "memory");
    } else {
      asm volatile("s_waitcnt vmcnt(0)" ::: "memory");
    }
    __builtin_amdgcn_sched_barrier(0);
    __builtin_amdgcn_s_barrier();
    const unsigned short* Ah = lds + (kt & 1) * 16384 + wr * 8192;
    const unsigned short* Bh =
        lds + 32768 + (kt & 1) * 16384 + (wc >> 1) * 8192;
    const int br0 = (wc & 1) * 64;

    // ---- ph0: read all B frags + A rf0; stage A0,A1(kt+1) ----
    bh8 bfr[2][4], af0[4];
#pragma unroll
    for (int nf = 0; nf < 2; ++nf)
#pragma unroll
      for (int kf = 0; kf < 4; ++kf) bfr[nf][kf] = BFRAG(nf, kf);
#pragma unroll
    for (int kf = 0; kf < 4; ++kf) af0[kf] = AFRAG(0, kf);
    if (kt + 1 < NT) { SA(kt + 1, 0); SA(kt + 1, 1); }
    __builtin_amdgcn_s_barrier();
    __builtin_amdgcn_s_setprio(1);
#pragma unroll
    for (int nf = 0; nf < 2; ++nf)
#pragma unroll
      for (int kf = 0; kf < 4; ++kf)
        acc[0][nf] = mfma32(bfr[nf][kf], af0[kf], acc[0][nf]);
    __builtin_amdgcn_s_setprio(0);
    __builtin_amdgcn_s_barrier();

    // ---- ph1: read A rf1; stage B0(kt+2) ----
    bh8 af1[4];
#pragma unroll
    for (int kf = 0; kf < 4; ++kf) af1[kf] = AFRAG(1, kf);
    if (kt + 2 < NT) SB(kt + 2, 0);
    __builtin_amdgcn_s_barrier();
    __builtin_amdgcn_s_setprio(1);
#pragma unroll
    for (int nf = 0; nf < 2; ++nf)
#pragma unroll
      for (int kf = 0; kf < 4; ++kf)
        acc[1][nf] = mfma32(bfr[nf][kf], af1[kf], acc[1][nf]);
    __builtin_amdgcn_s_setprio(0);
    __builtin_amdgcn_s_barrier();

    // ---- ph2: read A rf2; stage B1(kt+2) ----
    bh8 af2[4];
#pragma unroll
    for (int kf = 0; kf < 4; ++kf) af2[kf] = AFRAG(2, kf);
    if (kt + 2 < NT) SB(kt + 2, 1);
    __builtin_amdgcn_s_barrier();
    __builtin_amdgcn_s_setprio(1);
#pragma unroll
    for (int nf = 0; nf < 2; ++nf)
#pragma unroll
      for (int kf = 0; kf < 4; ++kf)
        acc[2][nf] = mfma32(bfr[nf][kf], af2[kf], acc[2][nf]);
    __builtin_amdgcn_s_setprio(0);
    __builtin_amdgcn_s_barrier();

    // ---- ph3: read A rf3 ----
    bh8 af3[4];
#pragma unroll
    for (int kf = 0; kf < 4; ++kf) af3[kf] = AFRAG(3, kf);
    __builtin_amdgcn_s_barrier();
    __builtin_amdgcn_s_setprio(1);
#pragma unroll
    for (int nf = 0; nf < 2; ++nf)
#pragma unroll
      for (int kf = 0; kf < 4; ++kf)
        acc[3][nf] = mfma32(bfr[nf][kf], af3[kf], acc[3][nf]);
    __builtin_amdgcn_s_setprio(0);
    // no trailing barrier: top-of-tile vmcnt+barrier follows
  }
#undef SA
#undef SB
#undef AFRAG
#undef BFRAG

  // epilogue — swapped operands: lane holds row = c31 (32 rows/frag),
  // cols = nf*32 + 8*g + 4*hi5 + j for reg r = 4g+j (4 consecutive cols)
  if (MODE == 0) {
    float bgv[2][4][4];
    if (wc == 3) {
#pragma unroll
      for (int nf = 0; nf < 2; ++nf)
#pragma unroll
        for (int g = 0; g < 4; ++g) {
          const float4 bv = *reinterpret_cast<const float4*>(
              bg + cb * 64 + nf * 32 + 8 * g + 4 * hi5);
          bgv[nf][g][0] = bv.x; bgv[nf][g][1] = bv.y;
          bgv[nf][g][2] = bv.z; bgv[nf][g][3] = bv.w;
        }
    }
    __syncthreads();  // all main-loop LDS reads retired
    // wc1/2: transpose-scatter k,v into LDS; wc0/3: activation math into regs
    // (global q/g stores DEFERRED past the last barrier so no vmcnt drain)
    ushort4 qg[4][2][4];
    if (wc == 1 || wc == 2) {
      unsigned short* dstT = lds + (wc == 2 ? 16896 : 0);
#pragma unroll
      for (int rf = 0; rf < 4; ++rf) {
        const int n = wr * 128 + rf * 32 + c31;
#pragma unroll
        for (int nf = 0; nf < 2; ++nf)
#pragma unroll
          for (int g = 0; g < 4; ++g)
#pragma unroll
            for (int j = 0; j < 4; ++j) {
              float v = acc[rf][nf][4 * g + j];
              if (wc == 1) v = elu1(v);
              const int d = nf * 32 + 8 * g + 4 * hi5 + j;
              dstT[d * 264 + n] = f2bf(v);
            }
      }
    } else {
#pragma unroll
      for (int rf = 0; rf < 4; ++rf)
#pragma unroll
        for (int nf = 0; nf < 2; ++nf)
#pragma unroll
          for (int g = 0; g < 4; ++g)
#pragma unroll
            for (int j = 0; j < 4; ++j) {
              float v = acc[rf][nf][4 * g + j];
              if (wc == 0) v = elu1(v);                                   // q
              else v = 1.f / (1.f + __expf(-(v + bgv[nf][g][j])));        // g
              ((unsigned short*)&qg[rf][nf][g])[j] = f2bf(v);
            }
    }
    __syncthreads();
    const unsigned short* kT = lds;
    const unsigned short* vT = lds + 16896;
    const size_t pbase = (size_t)((rb >> 4) * 16 + cb) * 16 + (rb & 15);
#pragma unroll
    for (int pi = 0; pi < 2; ++pi) {
      const int p = w * 2 + pi, dt = p >> 2, et = p & 3;
      f4v a = (f4v){0.f, 0.f, 0.f, 0.f};
#pragma unroll
      for (int kn = 0; kn < 8; ++kn) {
        const bh8 kq = *reinterpret_cast<const bh8*>(
            kT + (dt * 16 + c0) * 264 + kn * 32 + g4 * 8);
        const bh8 vq = *reinterpret_cast<const bh8*>(
            vT + (et * 16 + c0) * 264 + kn * 32 + g4 * 8);
        a = mfma16(vq, kq, a);  // d on c0, e on (g4,r)
      }
      float4 o;
      o.x = a[0]; o.y = a[1]; o.z = a[2]; o.w = a[3];
      *reinterpret_cast<float4*>(
          kv_part + pbase * 4096 + (dt * 16 + c0) * 64 + et * 16 + g4 * 4) = o;
    }
    if (w < 4) {  // ksum for d-tile w via ones operand
      bh8 ones;
#pragma unroll
      for (int j = 0; j < 8; ++j) ones[j] = (short)0x3F80;
      f4v a = (f4v){0.f, 0.f, 0.f, 0.f};
#pragma unroll
      for (int kn = 0; kn < 8; ++kn) {
        const bh8 kq = *reinterpret_cast<const bh8*>(
            kT + (w * 16 + c0) * 264 + kn * 32 + g4 * 8);
        a = mfma16(ones, kq, a);
      }
      if (lane < 16) ksum_part[pbase * 64 + w * 16 + c0] = a[0];
    }
    // deferred q/g stores (no barrier after these — latency hides in endpgm)
    if (wc == 0 || wc == 3) {
#pragma unroll
      for (int rf = 0; rf < 4; ++rf) {
        const size_t row = (size_t)rb * 256 + wr * 128 + rf * 32 + c31;
#pragma unroll
        for (int nf = 0; nf < 2; ++nf)
#pragma unroll
          for (int g = 0; g < 4; ++g)
            *reinterpret_cast<ushort4*>(
                ob + row * 4096 + cb * 256 + wc * 64 + nf * 32 + 8 * g +
                4 * hi5) = qg[rf][nf][g];
      }
    }
  } else {
#pragma unroll
    for (int rf = 0; rf < 4; ++rf) {
      const size_t row = (size_t)rb * 256 + wr * 128 + rf * 32 + c31;
#pragma unroll
      for (int nf = 0; nf < 2; ++nf)
#pragma unroll
        for (int g = 0; g < 4; ++g) {
          float4 o;
          o.x = acc[rf][nf][4 * g + 0];
          o.y = acc[rf][nf][4 * g + 1];
          o.z = acc[rf][nf][4 * g + 2];
          o.w = acc[rf][nf][4 * g + 3];
          *reinterpret_cast<float4*>(
              of + row * DIM + cb * 256 + wc * 64 + nf * 32 + 8 * g +
              4 * hi5) = o;
        }
    }
  }
}

// ---- G2r: reduce 16 partials -> kvT bf16 [bh][e][d], ksum fp32 -------------
// grid = nbat*64: 4 blocks per bh, each reduces a 1024-element quarter
__global__ __launch_bounds__(256) void g2r(const float* __restrict__ kv_part,
                                           const float* __restrict__ ksum_part,
                                           unsigned short* __restrict__ kvT,
                                           float* __restrict__ ksum, int b0) {
  const int blk = blockIdx.x, t = threadIdx.x;
  const int bhl = blk >> 2, qr = blk & 3;
  const size_t bh = (size_t)b0 * 16 + bhl;
#pragma unroll
  for (int i = 0; i < 4; ++i) {
    const int idx = qr * 1024 + i * 256 + t;
    const int d = idx >> 6, e = idx & 63;
    float s = 0.f;
    for (int sp = 0; sp < 16; ++sp)
      s += kv_part[((size_t)bhl * 16 + sp) * 4096 + idx];
    kvT[bh * 4096 + e * 64 + d] = f2bf(s);
  }
  if (qr == 0 && t < 64) {
    float s = 0.f;
    for (int sp = 0; sp < 16; ++sp)
      s += ksum_part[((size_t)bhl * 16 + sp) * 64 + t];
    ksum[bh * 64 + t] = s;
  }
}

// ---- G3: attn apply: o = q@kv * z * g -> DENSE bf16 attn buffer (xb) -------
// 256 rows per block (two 128-row halves; skv staged once)
__global__ __launch_bounds__(256) void g3(const unsigned short* __restrict__ qkvg,
                                          const unsigned short* __restrict__ kvT,
                                          const float* __restrict__ ksum,
                                          unsigned short* __restrict__ attn,
                                          int b0) {
  const int h = blockIdx.x, z = blockIdx.y;  // z in [0, nbat*16)
  const int t = threadIdx.x, lane = t & 63, w = t >> 6;
  const int g4 = lane >> 4, c0 = lane & 15;
  __shared__ unsigned short sQ[8192];
  __shared__ unsigned short skv[64 * 72];
  __shared__ float sks[64], sden[128];
  const int bb = z >> 4;
  const size_t bh = (size_t)(b0 + bb) * 16 + h;
  for (int i = t; i < 4096; i += 256)
    skv[(i >> 6) * 72 + (i & 63)] = kvT[bh * 4096 + i];
  if (t < 64) sks[t] = ksum[bh * 64 + t];
  for (int h2 = 0; h2 < 2; ++h2) {
    const size_t row0 = (size_t)z * 256 + h2 * 128;
    gll_tile(qkvg + row0 * 4096 + h * 256, 4096, sQ, t);
    __syncthreads();
    {
      const int rr = t >> 1, hf = t & 1;
      float s = 0.f;
#pragma unroll
      for (int dd = 0; dd < 32; ++dd) {
        const int d = hf * 32 + dd;
        s += bf2f(sQ[(((rr << 3) | (d >> 3)) ^ (rr & 7)) * 8 + (d & 7)]) *
             sks[d];
      }
      s += __shfl_xor(s, 1, 64);
      if (hf == 0) sden[rr] = SCALE / fmaxf(s, 1e-6f);
    }
    __syncthreads();
    f4v oacc[2][4];
#pragma unroll
    for (int ii = 0; ii < 2; ++ii)
#pragma unroll
      for (int et = 0; et < 4; ++et) oacc[ii][et] = (f4v){0.f, 0.f, 0.f, 0.f};
#pragma unroll
    for (int kf = 0; kf < 2; ++kf) {
      bh8 aq[2];
#pragma unroll
      for (int ii = 0; ii < 2; ++ii)
        aq[ii] = frag(sQ, w * 32 + ii * 16 + c0, kf * 4 + g4);
#pragma unroll
      for (int et = 0; et < 4; ++et) {
        const bh8 bkv = *reinterpret_cast<const bh8*>(
            skv + (et * 16 + c0) * 72 + kf * 32 + g4 * 8);
#pragma unroll
        for (int ii = 0; ii < 2; ++ii)
          oacc[ii][et] = mfma16(bkv, aq[ii], oacc[ii][et]);
      }
    }
#pragma unroll
    for (int ii = 0; ii < 2; ++ii) {
      const int n = w * 32 + ii * 16 + c0;
      const float z2 = sden[n];
#pragma unroll
      for (int et = 0; et < 4; ++et) {
        const ushort4 gt = *reinterpret_cast<const ushort4*>(
            qkvg + (row0 + n) * 4096 + h * 256 + 192 + et * 16 + g4 * 4);
        ushort4 o;
#pragma unroll
        for (int r = 0; r < 4; ++r)
          ((unsigned short*)&o)[r] =
              f2bf(oacc[ii][et][r] * z2 * bf2f(((const unsigned short*)&gt)[r]));
        *reinterpret_cast<ushort4*>(
            attn + (row0 + n) * 1024 + h * 64 + et * 16 + g4 * 4) = o;
      }
    }
    __syncthreads();  // sQ reads done before next half restages
  }
}

// ---------------------------------------------------------------------------
extern "C" void kernel_launch(void* const* d_in, const int* in_sizes, int n_in,
                              void* d_out, int out_size, void* d_ws,
                              size_t ws_size, hipStream_t stream) {
  const float* x  = (const float*)d_in[0];
  const float* Wq = (const float*)d_in[1];
  const float* Wk = (const float*)d_in[2];
  const float* Wv = (const float*)d_in[3];
  const float* Wg = (const float*)d_in[4];
  const float* bg = (const float*)d_in[5];
  const float* Wo = (const float*)d_in[6];
  float* out = (float*)d_out;
  char* w = (char*)d_ws;

  const size_t PB = 46202880ull;
  int nbat = 1;
  if (ws_size >= 11026432ull + 4ull * PB) nbat = 4;
  else if (ws_size >= 11026432ull + 2ull * PB) nbat = 2;

  unsigned short* WallT = (unsigned short*)(w);                  // 8 MiB
  unsigned short* WoT   = (unsigned short*)(w + 8388608);        // 2 MiB
  unsigned short* kvT   = (unsigned short*)(w + 10485760);       // 512 KiB
  float*          ksum  = (float*)(w + 11010048);                // 16 KiB
  char* dyn = w + 11026432;
  float* kv_part        = (float*)dyn;
  float* ksum_part      = (float*)(dyn + (size_t)nbat * 4194304);
  unsigned short* xb    = (unsigned short*)(dyn + (size_t)nbat * (4194304 + 65536));
  unsigned short* qkvg  = (unsigned short*)(dyn + (size_t)nbat * (4194304 + 65536 + 8388608));

  for (int b0 = 0; b0 < 4; b0 += nbat) {
    const int rows_p = nbat * 4096;
    const int np0 = rows_p / 2;
    p01<<<np0 + 1280, 256, 0, stream>>>(x + (size_t)b0 * 4096 * DIM, xb, np0,
                                        Wq, Wk, Wv, Wg, Wo, WallT, WoT,
                                        b0 == 0 ? 1 : 0);
    gemm8<0><<<dim3((rows_p / 256) * 16), 512, 0, stream>>>(
        xb, WallT, bg, qkvg, nullptr, kv_part, ksum_part);
    g2r<<<nbat * 64, 256, 0, stream>>>(kv_part, ksum_part, kvT, ksum, b0);
    // g3 overwrites xb (dead after gemm8<0>) with dense attn [rows][1024]
    g3<<<dim3(16, nbat * 16), 256, 0, stream>>>(qkvg, kvT, ksum, xb, b0);
    gemm8<1><<<dim3((rows_p / 256) * 4), 512, 0, stream>>>(
        xb, WoT, nullptr, nullptr, out + (size_t)b0 * 4096 * DIM,
        nullptr, nullptr);
  }
}

// Round 14
// 268.745 us; speedup vs baseline: 1.0939x; 1.0939x over previous
//
#include <hip/hip_runtime.h>
#include <math.h>

#define DIM 1024
#define SCALE 0.125f
#define NT 16  // K-tiles of 64

typedef __attribute__((ext_vector_type(8))) short bh8;
typedef __attribute__((ext_vector_type(4))) short bh4;
typedef __attribute__((ext_vector_type(4))) float f4v;

__device__ __forceinline__ unsigned short f2bf(float f) {
  unsigned u = __builtin_bit_cast(unsigned, f);
  return (unsigned short)((u + 0x7FFFu + ((u >> 16) & 1u)) >> 16);
}
__device__ __forceinline__ float bf2f(unsigned short u) {
  return __builtin_bit_cast(float, (unsigned)u << 16);
}
__device__ __forceinline__ float elu1(float v) {
  return v > 0.f ? v + 1.f : __expf(v);
}
__device__ __forceinline__ f4v mfma16(bh8 a, bh8 b, f4v c) {
  return __builtin_amdgcn_mfma_f32_16x16x32_bf16(a, b, c, 0, 0, 0);
}

typedef const void __attribute__((address_space(1)))* gas1_t;
typedef void __attribute__((address_space(3)))* las3_t;

// 128x64 bf16 half-tile in LDS as 1024 16B chunks, swizzle q = c ^ ((c>>3)&7)
__device__ __forceinline__ bh8 frag(const unsigned short* lds, int row, int k8) {
  const int q = ((row << 3) | k8) ^ (row & 7);
  return *reinterpret_cast<const bh8*>(lds + q * 8);
}

// 256-thread staging helper (used by g3): 128x64 tile, 4 chunks/thread
__device__ __forceinline__ void gll_tile(const unsigned short* g, int ldg,
                                         unsigned short* lds, int t) {
  const int lane = t & 63, w = t >> 6;
#pragma unroll
  for (int cc = 0; cc < 4; ++cc) {
    const int base = (w * 4 + cc) * 64;
    const int q = base + lane;
    const int c = q ^ ((q >> 3) & 7);
    __builtin_amdgcn_global_load_lds(
        (gas1_t)(const void*)(g + (size_t)(c >> 3) * ldg + (c & 7) * 8),
        (las3_t)(void*)(lds + (size_t)base * 8), 16, 0, 0);
  }
}

// ---- P01: fused x-cvt (blocks < np0) + weight transpose (first pass only) --
__global__ __launch_bounds__(256) void p01(
    const float* __restrict__ x, unsigned short* __restrict__ xb, int np0,
    const float* __restrict__ Wq, const float* __restrict__ Wk,
    const float* __restrict__ Wv, const float* __restrict__ Wg,
    const float* __restrict__ Wo, unsigned short* __restrict__ WallT,
    unsigned short* __restrict__ WoT, int do_w) {
  const int bid = (int)blockIdx.x;
  const int t = (int)threadIdx.x;
  if (bid < np0) {
    const size_t i = ((size_t)bid * 256 + t) * 8;
    const float4 a = *reinterpret_cast<const float4*>(x + i);
    const float4 b = *reinterpret_cast<const float4*>(x + i + 4);
    bh8 v;
    v[0] = (short)f2bf(a.x); v[1] = (short)f2bf(a.y);
    v[2] = (short)f2bf(a.z); v[3] = (short)f2bf(a.w);
    v[4] = (short)f2bf(b.x); v[5] = (short)f2bf(b.y);
    v[6] = (short)f2bf(b.z); v[7] = (short)f2bf(b.w);
    *reinterpret_cast<bh8*>(xb + i) = v;
    return;
  }
  if (!do_w) return;
  const int rem = bid - np0;
  const int m = rem >> 8;          // 0..4
  const int tc = rem & 15, tr = (rem >> 4) & 15;
  const float* src = m == 0 ? Wq : m == 1 ? Wk : m == 2 ? Wv : m == 3 ? Wg : Wo;
  __shared__ float tile[64][65];
#pragma unroll
  for (int i = 0; i < 4; ++i) {
    const int idx = i * 256 + t;
    const int r = idx >> 4;
    const int c4 = (idx & 15) * 4;
    const float4 v = *reinterpret_cast<const float4*>(
        src + (size_t)(tr * 64 + r) * DIM + tc * 64 + c4);
    tile[r][c4] = v.x; tile[r][c4 + 1] = v.y;
    tile[r][c4 + 2] = v.z; tile[r][c4 + 3] = v.w;
  }
  __syncthreads();
  unsigned short* dst = (m < 4) ? WallT : WoT;
#pragma unroll
  for (int i = 0; i < 4; ++i) {
    const int idx = i * 256 + t;
    const int lc = idx >> 4;
    const int k4i = (idx & 15) * 4;
    const size_t drow = (m < 4) ? (size_t)(tc * 256 + m * 64 + lc)
                                : (size_t)(tc * 64 + lc);
    bh4 v;
#pragma unroll
    for (int jj = 0; jj < 4; ++jj) v[jj] = (short)f2bf(tile[k4i + jj][lc]);
    *reinterpret_cast<bh4*>(dst + drow * DIM + tr * 64 + k4i) = v;
  }
}

// ---- gemm8: 256x256 tile, round-5 phase pipeline ----------------------------
// MODE 0: qkvg = xb @ WallT^T, fused activations + kv/ksum partials (MFMA);
//         only q,g columns stored to global (k,v are epilogue-consumed only)
// MODE 1: out = attn(dense, in xb) @ WoT^T, f32 out (1024 cols)
// Both modes: A is dense [rows][1024] bf16.
template <int MODE>
__global__ __launch_bounds__(512, 1) void gemm8(
    const unsigned short* __restrict__ gA,
    const unsigned short* __restrict__ gB, const float* __restrict__ bg,
    unsigned short* __restrict__ ob, float* __restrict__ of,
    float* __restrict__ kv_part, float* __restrict__ ksum_part) {
  const int t = threadIdx.x, lane = t & 63, w = t >> 6;
  const int wr = w >> 2, wc = w & 3, g4 = lane >> 4, c0 = lane & 15;
  const int nwg = gridDim.x;
  const int NBC = (MODE == 0) ? 16 : 4;
  const int rbn = nwg / NBC;
  // XCD row-band swizzle: XCD x owns rb in [x*bandsz, (x+1)*bandsz), cb-major
  const int bid = (int)blockIdx.x;
  const int xcd = bid & 7;
  const int idx = bid >> 3;
  const int bandsz = rbn >> 3;
  const int cb = idx / bandsz;
  const int rb = xcd * bandsz + (idx - cb * bandsz);

  __shared__ __align__(16) unsigned short lds[65536];  // 128 KiB

  // per-thread chunk offsets (2 chunks per half-tile stage)
  int offA[2], offB[2], dstc[2];
#pragma unroll
  for (int cc = 0; cc < 2; ++cc) {
    const int base = (w * 2 + cc) * 64;
    const int q = base + lane;
    const int c = q ^ ((q >> 3) & 7);
    offA[cc] = (c >> 3) * 1024 + (c & 7) * 8;
    offB[cc] = (c >> 3) * 1024 + (c & 7) * 8;
    dstc[cc] = base * 8;
  }
  const unsigned short* Abase = gA + (size_t)rb * 256 * 1024;
  const unsigned short* Bbase = gB + (size_t)cb * 256 * 1024;

#define SA(kt, half)                                                          \
  {                                                                           \
    _Pragma("unroll") for (int cc = 0; cc < 2; ++cc)                          \
        __builtin_amdgcn_global_load_lds(                                     \
            (gas1_t)(Abase + (size_t)(half) * 128 * 1024 + offA[cc] +         \
                     (kt) * 64),                                              \
            (las3_t)(lds + ((kt) & 1) * 16384 + (half) * 8192 + dstc[cc]),    \
            16, 0, 0);                                                        \
  }
#define SB(kt, half)                                                          \
  {                                                                           \
    _Pragma("unroll") for (int cc = 0; cc < 2; ++cc)                          \
        __builtin_amdgcn_global_load_lds(                                     \
            (gas1_t)(Bbase + (size_t)(half) * 128 * 1024 + offB[cc] +         \
                     (kt) * 64),                                              \
            (las3_t)(lds + 32768 + ((kt) & 1) * 16384 + (half) * 8192 +       \
                     dstc[cc]),                                               \
            16, 0, 0);                                                        \
  }

  f4v acc[8][4];
#pragma unroll
  for (int i = 0; i < 8; ++i)
#pragma unroll
    for (int j = 0; j < 4; ++j) acc[i][j] = (f4v){0.f, 0.f, 0.f, 0.f};

  // prologue: B(0), A(0) (awaited at tile 0), then B(1) halves (in flight)
  SB(0, 0); SB(0, 1); SA(0, 0); SA(0, 1); SB(1, 0); SB(1, 1);

#pragma unroll 2
  for (int kt = 0; kt < NT; ++kt) {
    // top-of-tile: all of tile kt landed; B(kt+1) halves may pend (4 loads)
    if (kt < NT - 1) {
      asm volatile("s_waitcnt vmcnt(4)" ::: "memory");
    } else {
      asm volatile("s_waitcnt vmcnt(0)" ::: "memory");
    }
    __builtin_amdgcn_sched_barrier(0);
    __builtin_amdgcn_s_barrier();
    const unsigned short* Ah = lds + (kt & 1) * 16384 + wr * 8192;
    const unsigned short* Bh =
        lds + 32768 + (kt & 1) * 16384 + (wc >> 1) * 8192;
    const int br0 = (wc & 1) * 64;

    // ---- ph0: read all B frags + A rf0-1; stage A0,A1(kt+1) ----
    bh8 bfr[4][2], a0[2][2];
#pragma unroll
    for (int nf = 0; nf < 4; ++nf)
#pragma unroll
      for (int kf = 0; kf < 2; ++kf)
        bfr[nf][kf] = frag(Bh, br0 + nf * 16 + c0, kf * 4 + g4);
#pragma unroll
    for (int i = 0; i < 2; ++i)
#pragma unroll
      for (int kf = 0; kf < 2; ++kf)
        a0[i][kf] = frag(Ah, i * 16 + c0, kf * 4 + g4);
    if (kt + 1 < NT) { SA(kt + 1, 0); SA(kt + 1, 1); }
    __builtin_amdgcn_s_barrier();
    __builtin_amdgcn_s_setprio(1);
#pragma unroll
    for (int i = 0; i < 2; ++i)
#pragma unroll
      for (int nf = 0; nf < 4; ++nf)
#pragma unroll
        for (int kf = 0; kf < 2; ++kf)
          acc[i][nf] = mfma16(bfr[nf][kf], a0[i][kf], acc[i][nf]);
    __builtin_amdgcn_s_setprio(0);
    __builtin_amdgcn_s_barrier();

    // ---- ph1: read A rf2-3; stage B0(kt+2) ----
    bh8 a1[2][2];
#pragma unroll
    for (int i = 0; i < 2; ++i)
#pragma unroll
      for (int kf = 0; kf < 2; ++kf)
        a1[i][kf] = frag(Ah, (2 + i) * 16 + c0, kf * 4 + g4);
    if (kt + 2 < NT) SB(kt + 2, 0);
    __builtin_amdgcn_s_barrier();
    __builtin_amdgcn_s_setprio(1);
#pragma unroll
    for (int i = 0; i < 2; ++i)
#pragma unroll
      for (int nf = 0; nf < 4; ++nf)
#pragma unroll
        for (int kf = 0; kf < 2; ++kf)
          acc[2 + i][nf] = mfma16(bfr[nf][kf], a1[i][kf], acc[2 + i][nf]);
    __builtin_amdgcn_s_setprio(0);
    __builtin_amdgcn_s_barrier();

    // ---- ph2: read A rf4-5; stage B1(kt+2) ----
    bh8 a2[2][2];
#pragma unroll
    for (int i = 0; i < 2; ++i)
#pragma unroll
      for (int kf = 0; kf < 2; ++kf)
        a2[i][kf] = frag(Ah, (4 + i) * 16 + c0, kf * 4 + g4);
    if (kt + 2 < NT) SB(kt + 2, 1);
    __builtin_amdgcn_s_barrier();
    __builtin_amdgcn_s_setprio(1);
#pragma unroll
    for (int i = 0; i < 2; ++i)
#pragma unroll
      for (int nf = 0; nf < 4; ++nf)
#pragma unroll
        for (int kf = 0; kf < 2; ++kf)
          acc[4 + i][nf] = mfma16(bfr[nf][kf], a2[i][kf], acc[4 + i][nf]);
    __builtin_amdgcn_s_setprio(0);
    __builtin_amdgcn_s_barrier();

    // ---- ph3: read A rf6-7 ----
    bh8 a3[2][2];
#pragma unroll
    for (int i = 0; i < 2; ++i)
#pragma unroll
      for (int kf = 0; kf < 2; ++kf)
        a3[i][kf] = frag(Ah, (6 + i) * 16 + c0, kf * 4 + g4);
    __builtin_amdgcn_s_barrier();
    __builtin_amdgcn_s_setprio(1);
#pragma unroll
    for (int i = 0; i < 2; ++i)
#pragma unroll
      for (int nf = 0; nf < 4; ++nf)
#pragma unroll
        for (int kf = 0; kf < 2; ++kf)
          acc[6 + i][nf] = mfma16(bfr[nf][kf], a3[i][kf], acc[6 + i][nf]);
    __builtin_amdgcn_s_setprio(0);
    // no trailing barrier: top-of-tile vmcnt+barrier follows
  }
#undef SA
#undef SB

  // epilogue — swapped operands: lane holds row = c0 (16 rows/frag),
  // cols = nf*16 + g4*4 + r (4 consecutive) -> vector stores
  if (MODE == 0) {
    float bgv[4][4];
    if (wc == 3) {
#pragma unroll
      for (int nf = 0; nf < 4; ++nf) {
        const float4 bv =
            *reinterpret_cast<const float4*>(bg + cb * 64 + nf * 16 + g4 * 4);
        bgv[nf][0] = bv.x; bgv[nf][1] = bv.y;
        bgv[nf][2] = bv.z; bgv[nf][3] = bv.w;
      }
    }
    __syncthreads();  // all main-loop LDS reads retired
    // wc1/2: transpose-scatter k,v into LDS; wc0/3: activation math into regs
    // (global q/g stores DEFERRED past the last barrier so no vmcnt drain)
    ushort4 qg[8][4];
    if (wc == 1 || wc == 2) {
      unsigned short* dstT = lds + (wc == 2 ? 16896 : 0);
#pragma unroll
      for (int rf = 0; rf < 8; ++rf) {
        const int n = wr * 128 + rf * 16 + c0;
#pragma unroll
        for (int nf = 0; nf < 4; ++nf)
#pragma unroll
          for (int r = 0; r < 4; ++r) {
            float v = acc[rf][nf][r];
            if (wc == 1) v = elu1(v);
            dstT[(nf * 16 + g4 * 4 + r) * 264 + n] = f2bf(v);
          }
      }
    } else {
#pragma unroll
      for (int rf = 0; rf < 8; ++rf)
#pragma unroll
        for (int nf = 0; nf < 4; ++nf)
#pragma unroll
          for (int r = 0; r < 4; ++r) {
            float v = acc[rf][nf][r];
            if (wc == 0) v = elu1(v);                                   // q
            else v = 1.f / (1.f + __expf(-(v + bgv[nf][r])));           // g
            ((unsigned short*)&qg[rf][nf])[r] = f2bf(v);
          }
    }
    __syncthreads();
    const unsigned short* kT = lds;
    const unsigned short* vT = lds + 16896;
    const size_t pbase = (size_t)((rb >> 4) * 16 + cb) * 16 + (rb & 15);
#pragma unroll
    for (int pi = 0; pi < 2; ++pi) {
      const int p = w * 2 + pi, dt = p >> 2, et = p & 3;
      f4v a = (f4v){0.f, 0.f, 0.f, 0.f};
#pragma unroll
      for (int kn = 0; kn < 8; ++kn) {
        const bh8 kq = *reinterpret_cast<const bh8*>(
            kT + (dt * 16 + c0) * 264 + kn * 32 + g4 * 8);
        const bh8 vq = *reinterpret_cast<const bh8*>(
            vT + (et * 16 + c0) * 264 + kn * 32 + g4 * 8);
        a = mfma16(vq, kq, a);  // d on c0, e on (g4,r)
      }
      float4 o;
      o.x = a[0]; o.y = a[1]; o.z = a[2]; o.w = a[3];
      *reinterpret_cast<float4*>(
          kv_part + pbase * 4096 + (dt * 16 + c0) * 64 + et * 16 + g4 * 4) = o;
    }
    if (w < 4) {  // ksum for d-tile w via ones operand
      bh8 ones;
#pragma unroll
      for (int j = 0; j < 8; ++j) ones[j] = (short)0x3F80;
      f4v a = (f4v){0.f, 0.f, 0.f, 0.f};
#pragma unroll
      for (int kn = 0; kn < 8; ++kn) {
        const bh8 kq = *reinterpret_cast<const bh8*>(
            kT + (w * 16 + c0) * 264 + kn * 32 + g4 * 8);
        a = mfma16(ones, kq, a);
      }
      if (lane < 16) ksum_part[pbase * 64 + w * 16 + c0] = a[0];
    }
    // deferred q/g stores (no barrier after these — latency hides in endpgm)
    if (wc == 0 || wc == 3) {
#pragma unroll
      for (int rf = 0; rf < 8; ++rf) {
        const size_t row = (size_t)rb * 256 + wr * 128 + rf * 16 + c0;
#pragma unroll
        for (int nf = 0; nf < 4; ++nf)
          *reinterpret_cast<ushort4*>(
              ob + row * 4096 + cb * 256 + wc * 64 + nf * 16 + g4 * 4) =
              qg[rf][nf];
      }
    }
  } else {
#pragma unroll
    for (int rf = 0; rf < 8; ++rf) {
      const size_t row = (size_t)rb * 256 + wr * 128 + rf * 16 + c0;
#pragma unroll
      for (int nf = 0; nf < 4; ++nf) {
        float4 o;
        o.x = acc[rf][nf][0]; o.y = acc[rf][nf][1];
        o.z = acc[rf][nf][2]; o.w = acc[rf][nf][3];
        *reinterpret_cast<float4*>(
            of + row * DIM + cb * 256 + wc * 64 + nf * 16 + g4 * 4) = o;
      }
    }
  }
}

// ---- G2r: reduce 16 partials -> kvT bf16 [bh][e][d], ksum fp32 -------------
// grid = nbat*64: 4 blocks per bh, each reduces a 1024-element quarter
__global__ __launch_bounds__(256) void g2r(const float* __restrict__ kv_part,
                                           const float* __restrict__ ksum_part,
                                           unsigned short* __restrict__ kvT,
                                           float* __restrict__ ksum, int b0) {
  const int blk = blockIdx.x, t = threadIdx.x;
  const int bhl = blk >> 2, qr = blk & 3;
  const size_t bh = (size_t)b0 * 16 + bhl;
#pragma unroll
  for (int i = 0; i < 4; ++i) {
    const int idx = qr * 1024 + i * 256 + t;
    const int d = idx >> 6, e = idx & 63;
    float s = 0.f;
    for (int sp = 0; sp < 16; ++sp)
      s += kv_part[((size_t)bhl * 16 + sp) * 4096 + idx];
    kvT[bh * 4096 + e * 64 + d] = f2bf(s);
  }
  if (qr == 0 && t < 64) {
    float s = 0.f;
    for (int sp = 0; sp < 16; ++sp)
      s += ksum_part[((size_t)bhl * 16 + sp) * 64 + t];
    ksum[bh * 64 + t] = s;
  }
}

// ---- G3: attn apply: o = q@kv * z * g -> DENSE bf16 attn buffer (xb) -------
// 256 rows per block (two 128-row halves; skv staged once)
__global__ __launch_bounds__(256) void g3(const unsigned short* __restrict__ qkvg,
                                          const unsigned short* __restrict__ kvT,
                                          const float* __restrict__ ksum,
                                          unsigned short* __restrict__ attn,
                                          int b0) {
  const int h = blockIdx.x, z = blockIdx.y;  // z in [0, nbat*16)
  const int t = threadIdx.x, lane = t & 63, w = t >> 6;
  const int g4 = lane >> 4, c0 = lane & 15;
  __shared__ unsigned short sQ[8192];
  __shared__ unsigned short skv[64 * 72];
  __shared__ float sks[64], sden[128];
  const int bb = z >> 4;
  const size_t bh = (size_t)(b0 + bb) * 16 + h;
  for (int i = t; i < 4096; i += 256)
    skv[(i >> 6) * 72 + (i & 63)] = kvT[bh * 4096 + i];
  if (t < 64) sks[t] = ksum[bh * 64 + t];
  for (int h2 = 0; h2 < 2; ++h2) {
    const size_t row0 = (size_t)z * 256 + h2 * 128;
    gll_tile(qkvg + row0 * 4096 + h * 256, 4096, sQ, t);
    __syncthreads();
    {
      const int rr = t >> 1, hf = t & 1;
      float s = 0.f;
#pragma unroll
      for (int dd = 0; dd < 32; ++dd) {
        const int d = hf * 32 + dd;
        s += bf2f(sQ[(((rr << 3) | (d >> 3)) ^ (rr & 7)) * 8 + (d & 7)]) *
             sks[d];
      }
      s += __shfl_xor(s, 1, 64);
      if (hf == 0) sden[rr] = SCALE / fmaxf(s, 1e-6f);
    }
    __syncthreads();
    f4v oacc[2][4];
#pragma unroll
    for (int ii = 0; ii < 2; ++ii)
#pragma unroll
      for (int et = 0; et < 4; ++et) oacc[ii][et] = (f4v){0.f, 0.f, 0.f, 0.f};
#pragma unroll
    for (int kf = 0; kf < 2; ++kf) {
      bh8 aq[2];
#pragma unroll
      for (int ii = 0; ii < 2; ++ii)
        aq[ii] = frag(sQ, w * 32 + ii * 16 + c0, kf * 4 + g4);
#pragma unroll
      for (int et = 0; et < 4; ++et) {
        const bh8 bkv = *reinterpret_cast<const bh8*>(
            skv + (et * 16 + c0) * 72 + kf * 32 + g4 * 8);
#pragma unroll
        for (int ii = 0; ii < 2; ++ii)
          oacc[ii][et] = mfma16(bkv, aq[ii], oacc[ii][et]);
      }
    }
#pragma unroll
    for (int ii = 0; ii < 2; ++ii) {
      const int n = w * 32 + ii * 16 + c0;
      const float z2 = sden[n];
#pragma unroll
      for (int et = 0; et < 4; ++et) {
        const ushort4 gt = *reinterpret_cast<const ushort4*>(
            qkvg + (row0 + n) * 4096 + h * 256 + 192 + et * 16 + g4 * 4);
        ushort4 o;
#pragma unroll
        for (int r = 0; r < 4; ++r)
          ((unsigned short*)&o)[r] =
              f2bf(oacc[ii][et][r] * z2 * bf2f(((const unsigned short*)&gt)[r]));
        *reinterpret_cast<ushort4*>(
            attn + (row0 + n) * 1024 + h * 64 + et * 16 + g4 * 4) = o;
      }
    }
    __syncthreads();  // sQ reads done before next half restages
  }
}

// ---------------------------------------------------------------------------
extern "C" void kernel_launch(void* const* d_in, const int* in_sizes, int n_in,
                              void* d_out, int out_size, void* d_ws,
                              size_t ws_size, hipStream_t stream) {
  const float* x  = (const float*)d_in[0];
  const float* Wq = (const float*)d_in[1];
  const float* Wk = (const float*)d_in[2];
  const float* Wv = (const float*)d_in[3];
  const float* Wg = (const float*)d_in[4];
  const float* bg = (const float*)d_in[5];
  const float* Wo = (const float*)d_in[6];
  float* out = (float*)d_out;
  char* w = (char*)d_ws;

  const size_t PB = 46202880ull;
  int nbat = 1;
  if (ws_size >= 11026432ull + 4ull * PB) nbat = 4;
  else if (ws_size >= 11026432ull + 2ull * PB) nbat = 2;

  unsigned short* WallT = (unsigned short*)(w);                  // 8 MiB
  unsigned short* WoT   = (unsigned short*)(w + 8388608);        // 2 MiB
  unsigned short* kvT   = (unsigned short*)(w + 10485760);       // 512 KiB
  float*          ksum  = (float*)(w + 11010048);                // 16 KiB
  char* dyn = w + 11026432;
  float* kv_part        = (float*)dyn;
  float* ksum_part      = (float*)(dyn + (size_t)nbat * 4194304);
  unsigned short* xb    = (unsigned short*)(dyn + (size_t)nbat * (4194304 + 65536));
  unsigned short* qkvg  = (unsigned short*)(dyn + (size_t)nbat * (4194304 + 65536 + 8388608));

  for (int b0 = 0; b0 < 4; b0 += nbat) {
    const int rows_p = nbat * 4096;
    const int np0 = rows_p / 2;
    p01<<<np0 + 1280, 256, 0, stream>>>(x + (size_t)b0 * 4096 * DIM, xb, np0,
                                        Wq, Wk, Wv, Wg, Wo, WallT, WoT,
                                        b0 == 0 ? 1 : 0);
    gemm8<0><<<dim3((rows_p / 256) * 16), 512, 0, stream>>>(
        xb, WallT, bg, qkvg, nullptr, kv_part, ksum_part);
    g2r<<<nbat * 64, 256, 0, stream>>>(kv_part, ksum_part, kvT, ksum, b0);
    // g3 overwrites xb (dead after gemm8<0>) with dense attn [rows][1024]
    g3<<<dim3(16, nbat * 16), 256, 0, stream>>>(qkvg, kvT, ksum, xb, b0);
    gemm8<1><<<dim3((rows_p / 256) * 4), 512, 0, stream>>>(
        xb, WoT, nullptr, nullptr, out + (size_t)b0 * 4096 * DIM,
        nullptr, nullptr);
  }
}